// Round 2
// baseline (1039.253 us; speedup 1.0000x reference)
//
#include <hip/hip_runtime.h>

// ---------------------------------------------------------------------------
// Decoder step: attention (enc@W1^T fused tanh/softmax/ctx) + GRU + fc head.
// Round 2: software-pipelined attn (1 barrier/kt, reg-prefetch staging),
// fused prep (1 kernel), fused key+gh GEMM, pipelined gemm_bt.
// ---------------------------------------------------------------------------

typedef __attribute__((ext_vector_type(4))) float floatx4;
typedef __attribute__((ext_vector_type(8))) short short8;
typedef unsigned short us;

#define DEV static __device__ __forceinline__

DEV us f2bf(float f) {                      // fp32 -> bf16, round-nearest-even
  unsigned u = __float_as_uint(f);
  u = u + 0x7fffu + ((u >> 16) & 1u);
  return (us)(u >> 16);
}
DEV float bf2f(us s) { return __uint_as_float(((unsigned)s) << 16); }
DEV float tanh_fast(float x) {
  float e = __expf(2.f * x);
  return 1.f - 2.f / (e + 1.f);
}
DEV float sigmoid_fast(float x) { return 1.f / (1.f + __expf(-x)); }
DEV unsigned pack2(float a, float b) {
  return (unsigned)f2bf(a) | ((unsigned)f2bf(b) << 16);
}

// ---------------------------------------------------------------------------
// Fused prep: all weight fp32->bf16 conversions (with padding), combined
// bias, embedding gather. One launch. Segment bounds are compile-time.
// ---------------------------------------------------------------------------
#define S0 262144    /* W1bf   512x512                       */
#define S1 1310720   /* wcomb  2048x512 = [W2;whh]           */
#define S2 2588672   /* wihbf  1536x832 (pad 812->832)       */
#define S3 2785280   /* fc1wbf 384x512  (rows pad 300->384)  */
#define S4 2834432   /* fc2wbf 128x384  (cols pad 300->384)  */
#define S5 3883008   /* hidbf  2048x512                      */
#define S6 3885056   /* bcomb  2048 f32 = [W1b+W2b; bhh]     */
#define S7 3885440   /* fc1bp  384 f32                       */
#define S8 4540800   /* emb -> ginbf cols [512,832)          */

__global__ void prep_kernel(const float* __restrict__ W1w,
                            const float* __restrict__ W2w,
                            const float* __restrict__ whh,
                            const float* __restrict__ wih,
                            const float* __restrict__ fc1w,
                            const float* __restrict__ fc2w,
                            const float* __restrict__ hidden,
                            const float* __restrict__ W1b,
                            const float* __restrict__ W2b,
                            const float* __restrict__ bhh,
                            const float* __restrict__ fc1b,
                            const int* __restrict__ x,
                            const float* __restrict__ embt,
                            us* __restrict__ W1bf, us* __restrict__ wcomb,
                            us* __restrict__ wihbf, us* __restrict__ fc1wbf,
                            us* __restrict__ fc2wbf, us* __restrict__ hidbf,
                            float* __restrict__ bcomb,
                            float* __restrict__ fc1bp,
                            us* __restrict__ ginbf) {
  int idx = blockIdx.x * 256 + threadIdx.x;
  if (idx < S0) {
    W1bf[idx] = f2bf(W1w[idx]);
  } else if (idx < S1) {
    int i = idx - S0, n = i >> 9, k = i & 511;
    float v = (n < 512) ? W2w[i] : whh[(size_t)(n - 512) * 512 + k];
    wcomb[i] = f2bf(v);
  } else if (idx < S2) {
    int i = idx - S1, n = i / 832, k = i - n * 832;
    wihbf[i] = f2bf(k < 812 ? wih[(size_t)n * 812 + k] : 0.f);
  } else if (idx < S3) {
    int i = idx - S2, n = i >> 9;
    fc1wbf[i] = f2bf(n < 300 ? fc1w[i] : 0.f);
  } else if (idx < S4) {
    int i = idx - S3, n = i / 384, k = i - n * 384;
    fc2wbf[i] = f2bf(k < 300 ? fc2w[(size_t)n * 300 + k] : 0.f);
  } else if (idx < S5) {
    int i = idx - S4;
    hidbf[i] = f2bf(hidden[i]);
  } else if (idx < S6) {
    int i = idx - S5;
    bcomb[i] = (i < 512) ? (W1b[i] + W2b[i]) : bhh[i - 512];
  } else if (idx < S7) {
    int i = idx - S6;
    fc1bp[i] = (i < 300) ? fc1b[i] : 0.f;
  } else if (idx < S8) {
    int i = idx - S7, b = i / 320, e = i - b * 320;
    float v = (e < 300) ? embt[(size_t)x[b] * 300 + e] : 0.f;
    ginbf[(size_t)b * 832 + 512 + e] = f2bf(v);
  }
}

// ---------------------------------------------------------------------------
// Generic bf16 GEMM with register-prefetch pipeline: C = A@B^T + bias.
// Block tile 128x128, 256 thr. Loads for kt+1 issued right after the barrier
// so they stay in flight across the MFMA phase.
// EPI 0: f32 store.  EPI 1: leaky_relu(0.01) -> bf16 store.
// ---------------------------------------------------------------------------
template <int EPI>
__global__ __launch_bounds__(256, 3) void gemm_bt(
    const us* __restrict__ A, int lda, const us* __restrict__ Bm, int ldb,
    const float* __restrict__ bias, void* __restrict__ Cp, int ldc, int K) {
  __shared__ us As[128 * 64];
  __shared__ us Bs[128 * 64];
  int tid = threadIdx.x;
  int bm = blockIdx.x * 128, bn = blockIdx.y * 128;
  int lane = tid & 63, wave = tid >> 6;
  int l15 = lane & 15, l4 = lane >> 4;
  int wm = (wave >> 1) * 64, wn = (wave & 1) * 64;

  floatx4 zero = {0.f, 0.f, 0.f, 0.f};
  floatx4 acc[4][4];
#pragma unroll
  for (int i = 0; i < 4; ++i)
#pragma unroll
    for (int j = 0; j < 4; ++j) acc[i][j] = zero;

  int row = tid >> 1;
  int gc0 = (tid & 1) * 4;
  const us* Aptr = A + (size_t)(bm + row) * lda + gc0 * 8;
  const us* Bptr = Bm + (size_t)(bn + row) * ldb + gc0 * 8;
  int rslot7 = row & 7, lslot7 = l15 & 7;

  uint4 pa[4], pb[4];
#pragma unroll
  for (int i = 0; i < 4; ++i) {
    pa[i] = *(const uint4*)(Aptr + i * 8);
    pb[i] = *(const uint4*)(Bptr + i * 8);
  }

  int nk = K >> 6;
  for (int kt = 0; kt < nk; ++kt) {
    if (kt) __syncthreads();          // WAR: LDS reuse
#pragma unroll
    for (int i = 0; i < 4; ++i) {
      int slot = (gc0 + i) ^ rslot7;
      *(uint4*)&As[row * 64 + slot * 8] = pa[i];
      *(uint4*)&Bs[row * 64 + slot * 8] = pb[i];
    }
    __syncthreads();
    if (kt + 1 < nk) {
#pragma unroll
      for (int i = 0; i < 4; ++i) {
        pa[i] = *(const uint4*)(Aptr + (kt + 1) * 64 + i * 8);
        pb[i] = *(const uint4*)(Bptr + (kt + 1) * 64 + i * 8);
      }
    }
#pragma unroll
    for (int ks = 0; ks < 2; ++ks) {
      int slot = (ks * 4 + l4) ^ lslot7;
      short8 av[4], bv[4];
#pragma unroll
      for (int mt = 0; mt < 4; ++mt)
        av[mt] = *(const short8*)&As[(wm + mt * 16 + l15) * 64 + slot * 8];
#pragma unroll
      for (int nt = 0; nt < 4; ++nt)
        bv[nt] = *(const short8*)&Bs[(wn + nt * 16 + l15) * 64 + slot * 8];
#pragma unroll
      for (int mt = 0; mt < 4; ++mt)
#pragma unroll
        for (int nt = 0; nt < 4; ++nt)
          acc[mt][nt] = __builtin_amdgcn_mfma_f32_16x16x32_bf16(
              av[mt], bv[nt], acc[mt][nt], 0, 0, 0);
    }
  }

#pragma unroll
  for (int nt = 0; nt < 4; ++nt) {
    int n = bn + wn + nt * 16 + l15;
    float bvv = bias[n];
#pragma unroll
    for (int mt = 0; mt < 4; ++mt) {
#pragma unroll
      for (int r = 0; r < 4; ++r) {
        int m = bm + wm + mt * 16 + l4 * 4 + r;
        float v = acc[mt][nt][r] + bvv;
        if (EPI == 1) {
          v = v > 0.f ? v : 0.01f * v;
          ((us*)Cp)[(size_t)m * ldc + n] = f2bf(v);
        } else {
          ((float*)Cp)[(size_t)m * ldc + n] = v;
        }
      }
    }
  }
}

// ---------------------------------------------------------------------------
// Fused attention, pipelined. One block (512 thr, 8 waves) per batch row b.
// enc[b] staged to LDS bf16 in 8 K-tiles of 128x64 (all distinct LDS -> one
// barrier per kt; loads for kt+1 in flight across MFMA of kt). W1 B-frags
// streamed from L2-hot global. Epilogue: tanh dot Vw -> logits -> softmax ->
// ctx from the LDS-resident enc copy. enc read from HBM exactly once.
// ---------------------------------------------------------------------------
#define ATTN_LDS_BYTES (131072 + 512 + 512 + 2048)

__global__ __launch_bounds__(512, 2) void attn_kernel(
    const float* __restrict__ enc, const us* __restrict__ W1b16,
    const float* __restrict__ keygh, const float* __restrict__ Vw,
    us* __restrict__ gin) {
  extern __shared__ unsigned char smem[];
  us* Albs = (us*)smem;                               // 8 tiles x [128][64]
  float* lds_logits = (float*)(smem + 131072);        // 128 f32
  float* lds_attw = lds_logits + 128;                 // 128 f32
  float* lds_ctx = lds_attw + 128;                    // 512 f32

  int b = blockIdx.x, tid = threadIdx.x;
  const float* encb = enc + (size_t)b * 65536;
  if (tid < 128) lds_logits[tid] = 0.f;

  int wave = tid >> 6, lane = tid & 63;
  int l15 = lane & 15, l4 = lane >> 4, lslot7 = l15 & 7;
  int n0 = wave * 64;

  // staging map: thread t -> row t>>2, granules (t&3) and (t&3)+4
  int srow = tid >> 2, g0 = tid & 3;
  int c7 = srow & 7;
  int slotA = g0 ^ c7, slotB = (g0 + 4) ^ c7;
  const float* sp = encb + srow * 512 + g0 * 8;       // +32 floats for g0+4
  us* wbase = Albs + srow * 64;

  floatx4 zero = {0.f, 0.f, 0.f, 0.f};
  floatx4 acc[8][4];
#pragma unroll
  for (int i = 0; i < 8; ++i)
#pragma unroll
    for (int j = 0; j < 4; ++j) acc[i][j] = zero;

  float4 p0, p1, p2, p3;                              // prefetch kt=0
  p0 = *(const float4*)(sp + 0);
  p1 = *(const float4*)(sp + 4);
  p2 = *(const float4*)(sp + 32);
  p3 = *(const float4*)(sp + 36);

  for (int kt = 0; kt < 8; ++kt) {
    uint4 qa, qb;
    qa.x = pack2(p0.x, p0.y); qa.y = pack2(p0.z, p0.w);
    qa.z = pack2(p1.x, p1.y); qa.w = pack2(p1.z, p1.w);
    qb.x = pack2(p2.x, p2.y); qb.y = pack2(p2.z, p2.w);
    qb.z = pack2(p3.x, p3.y); qb.w = pack2(p3.z, p3.w);
    us* wb = wbase + kt * 8192;
    *(uint4*)(wb + slotA * 8) = qa;
    *(uint4*)(wb + slotB * 8) = qb;
    __syncthreads();                                  // writes(kt) -> reads(kt)
    if (kt < 7) {
      const float* np = sp + (kt + 1) * 64;
      p0 = *(const float4*)(np + 0);
      p1 = *(const float4*)(np + 4);
      p2 = *(const float4*)(np + 32);
      p3 = *(const float4*)(np + 36);
    }
#pragma unroll
    for (int ks = 0; ks < 2; ++ks) {
      short8 av[8], bv[4];
#pragma unroll
      for (int nt = 0; nt < 4; ++nt) {
        int n = n0 + nt * 16 + l15;
        bv[nt] = *(const short8*)(W1b16 + (size_t)n * 512 + kt * 64 +
                                  ks * 32 + l4 * 8);
      }
      int slot = (ks * 4 + l4) ^ lslot7;
      const us* rb = Albs + kt * 8192;
#pragma unroll
      for (int mt = 0; mt < 8; ++mt)
        av[mt] = *(const short8*)(rb + (mt * 16 + l15) * 64 + slot * 8);
#pragma unroll
      for (int mt = 0; mt < 8; ++mt)
#pragma unroll
        for (int nt = 0; nt < 4; ++nt)
          acc[mt][nt] = __builtin_amdgcn_mfma_f32_16x16x32_bf16(
              av[mt], bv[nt], acc[mt][nt], 0, 0, 0);
    }
  }

  // ---- epilogue: logits[s] += sum_j tanh(score+key[j]) * Vw[j] ----
  float kb[4], vwl[4];
#pragma unroll
  for (int nt = 0; nt < 4; ++nt) {
    int col = n0 + nt * 16 + l15;
    kb[nt] = keygh[(size_t)b * 2048 + col];
    vwl[nt] = Vw[col];
  }
#pragma unroll
  for (int mt = 0; mt < 8; ++mt) {
#pragma unroll
    for (int r = 0; r < 4; ++r) {
      float c = 0.f;
#pragma unroll
      for (int nt = 0; nt < 4; ++nt)
        c += tanh_fast(acc[mt][nt][r] + kb[nt]) * vwl[nt];
      c += __shfl_xor(c, 1, 64);
      c += __shfl_xor(c, 2, 64);
      c += __shfl_xor(c, 4, 64);
      c += __shfl_xor(c, 8, 64);
      if (l15 == 0) atomicAdd(&lds_logits[mt * 16 + l4 * 4 + r], c);
    }
  }
  __syncthreads();

  // ---- softmax over S=128 (wave 0; V_b dropped: shift-invariant) ----
  if (wave == 0) {
    float v0 = lds_logits[lane], v1 = lds_logits[lane + 64];
    float mx = fmaxf(v0, v1);
#pragma unroll
    for (int o = 32; o >= 1; o >>= 1) mx = fmaxf(mx, __shfl_xor(mx, o, 64));
    float e0 = __expf(v0 - mx), e1 = __expf(v1 - mx);
    float s = e0 + e1;
#pragma unroll
    for (int o = 32; o >= 1; o >>= 1) s += __shfl_xor(s, o, 64);
    float inv = 1.f / s;
    lds_attw[lane] = e0 * inv;
    lds_attw[lane + 64] = e1 * inv;
  }
  __syncthreads();

  // ---- ctx: thread handles h-pair (dword), half the s-range ----
  int pr = tid & 255, sh = tid >> 8;
  int h0 = pr * 2;
  int ktc = h0 >> 6, gclc = (h0 & 63) >> 3, dofs = (pr & 3) * 2;  // shorts
  const us* cb = Albs + ktc * 8192;
  float c0 = 0.f, c1 = 0.f;
  int sbeg = sh * 64;
  for (int s = sbeg; s < sbeg + 64; ++s) {
    int slot = gclc ^ (s & 7);
    unsigned d = *(const unsigned*)(cb + s * 64 + slot * 8 + dofs);
    float aw = lds_attw[s];
    c0 += aw * bf2f((us)(d & 0xffffu));
    c1 += aw * bf2f((us)(d >> 16));
  }
  if (sh == 0) { lds_ctx[h0] = c0; lds_ctx[h0 + 1] = c1; }
  __syncthreads();
  if (sh == 1) {
    unsigned pk = pack2(lds_ctx[h0] + c0, lds_ctx[h0 + 1] + c1);
    *(unsigned*)(gin + (size_t)b * 832 + h0) = pk;
  }
}

// ---------------------------------------------------------------------------
// GRU elementwise: gh lives in keygh cols [512,2048).
// ---------------------------------------------------------------------------
__global__ void gru_kernel(const float* __restrict__ gi,
                           const float* __restrict__ keygh,
                           const float* __restrict__ hidden,
                           float* __restrict__ outh,
                           us* __restrict__ hnewbf) {
  int idx = blockIdx.x * 256 + threadIdx.x;   // 2048*512
  int b = idx >> 9, h = idx & 511;
  const float* gib = gi + (size_t)b * 1536;
  const float* ghb = keygh + (size_t)b * 2048 + 512;
  float r = sigmoid_fast(gib[h] + ghb[h]);
  float z = sigmoid_fast(gib[512 + h] + ghb[512 + h]);
  float n = tanh_fast(gib[1024 + h] + r * ghb[1024 + h]);
  float h0 = hidden[idx];
  float hn = (1.f - z) * n + z * h0;
  outh[idx] = hn;
  hnewbf[idx] = f2bf(hn);
}

// ---------------------------------------------------------------------------
extern "C" void kernel_launch(void* const* d_in, const int* in_sizes, int n_in,
                              void* d_out, int out_size, void* d_ws,
                              size_t ws_size, hipStream_t stream) {
  const int* x = (const int*)d_in[0];
  const float* hidden = (const float*)d_in[1];
  const float* enc = (const float*)d_in[2];
  const float* embt = (const float*)d_in[3];
  const float* W1w = (const float*)d_in[4];
  const float* W1b = (const float*)d_in[5];
  const float* W2w = (const float*)d_in[6];
  const float* W2b = (const float*)d_in[7];
  const float* Vw = (const float*)d_in[8];
  const float* wih = (const float*)d_in[10];
  const float* whh = (const float*)d_in[11];
  const float* bih = (const float*)d_in[12];
  const float* bhh = (const float*)d_in[13];
  const float* fc1w = (const float*)d_in[14];
  const float* fc1b = (const float*)d_in[15];
  const float* fc2w = (const float*)d_in[16];
  const float* fc2b = (const float*)d_in[17];

  float* out_y = (float*)d_out;                  // (2048,128)
  float* out_h = out_y + 2048 * 128;             // (2048,512)

  char* ws = (char*)d_ws;
  size_t o = 0;
  auto alloc = [&](size_t bytes) {
    size_t r = o;
    o += (bytes + 255) & ~(size_t)255;
    return r;
  };
  us* W1bf   = (us*)(ws + alloc(512 * 512 * 2));
  us* wcomb  = (us*)(ws + alloc(2048 * 512 * 2));
  us* wihbf  = (us*)(ws + alloc(1536 * 832 * 2));
  us* fc1wbf = (us*)(ws + alloc(384 * 512 * 2));
  us* fc2wbf = (us*)(ws + alloc(128 * 384 * 2));
  us* hidbf  = (us*)(ws + alloc(2048 * 512 * 2));
  float* bcomb = (float*)(ws + alloc(2048 * 4));
  float* fc1bp = (float*)(ws + alloc(384 * 4));
  us* ginbf  = (us*)(ws + alloc((size_t)2048 * 832 * 2));
  float* keygh = (float*)(ws + alloc((size_t)2048 * 2048 * 4));
  float* gi    = (float*)(ws + alloc((size_t)2048 * 1536 * 4));
  us* hnewbf = (us*)(ws + alloc(2048 * 512 * 2));
  us* a1bf   = (us*)(ws + alloc((size_t)2048 * 384 * 2));

  // 1) fused prep
  prep_kernel<<<(S8 + 255) / 256, 256, 0, stream>>>(
      W1w, W2w, whh, wih, fc1w, fc2w, hidden, W1b, W2b, bhh, fc1b, x, embt,
      W1bf, wcomb, wihbf, fc1wbf, fc2wbf, hidbf, bcomb, fc1bp, ginbf);

  // 2) keygh = h0 @ [W2;whh]^T + [W1b+W2b; bhh]   (2048x2048)
  gemm_bt<0><<<dim3(16, 16), 256, 0, stream>>>(hidbf, 512, wcomb, 512, bcomb,
                                               (void*)keygh, 2048, 512);

  // 3) fused attention -> ctx into gin[:, 0:512]
  (void)hipFuncSetAttribute((const void*)attn_kernel,
                            hipFuncAttributeMaxDynamicSharedMemorySize,
                            ATTN_LDS_BYTES);
  attn_kernel<<<2048, 512, ATTN_LDS_BYTES, stream>>>(enc, W1bf, keygh, Vw,
                                                     ginbf);

  // 4) gi = gin @ w_ih^T + b_ih   (2048x1536, K=832)
  gemm_bt<0><<<dim3(16, 12), 256, 0, stream>>>(ginbf, 832, wihbf, 832, bih,
                                               (void*)gi, 1536, 832);

  // 5) GRU gates -> h_new (f32 out + bf16 copy)
  gru_kernel<<<2048 * 512 / 256, 256, 0, stream>>>(gi, keygh, hidden, out_h,
                                                   hnewbf);

  // 6) head
  gemm_bt<1><<<dim3(16, 3), 256, 0, stream>>>(hnewbf, 512, fc1wbf, 512, fc1bp,
                                              (void*)a1bf, 384, 512);
  gemm_bt<0><<<dim3(16, 1), 256, 0, stream>>>(a1bf, 384, fc2wbf, 384, fc2b,
                                              (void*)out_y, 128, 384);
}

// Round 3
// 1021.698 us; speedup vs baseline: 1.0172x; 1.0172x over previous
//
#include <hip/hip_runtime.h>

// ---------------------------------------------------------------------------
// Decoder step: attention (enc@W1^T fused tanh/softmax/ctx) + GRU + fc head.
// Round 3: attn with 1024 threads (16 waves = 4/SIMD latency hiding at the
// forced 1-block/CU residency), bv-before-prefetch load ordering so vmcnt
// waits on W1 frags don't drain the enc prefetch.
// ---------------------------------------------------------------------------

typedef __attribute__((ext_vector_type(4))) float floatx4;
typedef __attribute__((ext_vector_type(8))) short short8;
typedef unsigned short us;

#define DEV static __device__ __forceinline__

DEV us f2bf(float f) {                      // fp32 -> bf16, round-nearest-even
  unsigned u = __float_as_uint(f);
  u = u + 0x7fffu + ((u >> 16) & 1u);
  return (us)(u >> 16);
}
DEV float bf2f(us s) { return __uint_as_float(((unsigned)s) << 16); }
DEV float tanh_fast(float x) {
  float e = __expf(2.f * x);
  return 1.f - 2.f / (e + 1.f);
}
DEV float sigmoid_fast(float x) { return 1.f / (1.f + __expf(-x)); }
DEV unsigned pack2(float a, float b) {
  return (unsigned)f2bf(a) | ((unsigned)f2bf(b) << 16);
}

// ---------------------------------------------------------------------------
// Fused prep (unchanged from R2).
// ---------------------------------------------------------------------------
#define S0 262144    /* W1bf   512x512                       */
#define S1 1310720   /* wcomb  2048x512 = [W2;whh]           */
#define S2 2588672   /* wihbf  1536x832 (pad 812->832)       */
#define S3 2785280   /* fc1wbf 384x512  (rows pad 300->384)  */
#define S4 2834432   /* fc2wbf 128x384  (cols pad 300->384)  */
#define S5 3883008   /* hidbf  2048x512                      */
#define S6 3885056   /* bcomb  2048 f32 = [W1b+W2b; bhh]     */
#define S7 3885440   /* fc1bp  384 f32                       */
#define S8 4540800   /* emb -> ginbf cols [512,832)          */

__global__ void prep_kernel(const float* __restrict__ W1w,
                            const float* __restrict__ W2w,
                            const float* __restrict__ whh,
                            const float* __restrict__ wih,
                            const float* __restrict__ fc1w,
                            const float* __restrict__ fc2w,
                            const float* __restrict__ hidden,
                            const float* __restrict__ W1b,
                            const float* __restrict__ W2b,
                            const float* __restrict__ bhh,
                            const float* __restrict__ fc1b,
                            const int* __restrict__ x,
                            const float* __restrict__ embt,
                            us* __restrict__ W1bf, us* __restrict__ wcomb,
                            us* __restrict__ wihbf, us* __restrict__ fc1wbf,
                            us* __restrict__ fc2wbf, us* __restrict__ hidbf,
                            float* __restrict__ bcomb,
                            float* __restrict__ fc1bp,
                            us* __restrict__ ginbf) {
  int idx = blockIdx.x * 256 + threadIdx.x;
  if (idx < S0) {
    W1bf[idx] = f2bf(W1w[idx]);
  } else if (idx < S1) {
    int i = idx - S0, n = i >> 9, k = i & 511;
    float v = (n < 512) ? W2w[i] : whh[(size_t)(n - 512) * 512 + k];
    wcomb[i] = f2bf(v);
  } else if (idx < S2) {
    int i = idx - S1, n = i / 832, k = i - n * 832;
    wihbf[i] = f2bf(k < 812 ? wih[(size_t)n * 812 + k] : 0.f);
  } else if (idx < S3) {
    int i = idx - S2, n = i >> 9;
    fc1wbf[i] = f2bf(n < 300 ? fc1w[i] : 0.f);
  } else if (idx < S4) {
    int i = idx - S3, n = i / 384, k = i - n * 384;
    fc2wbf[i] = f2bf(k < 300 ? fc2w[(size_t)n * 300 + k] : 0.f);
  } else if (idx < S5) {
    int i = idx - S4;
    hidbf[i] = f2bf(hidden[i]);
  } else if (idx < S6) {
    int i = idx - S5;
    bcomb[i] = (i < 512) ? (W1b[i] + W2b[i]) : bhh[i - 512];
  } else if (idx < S7) {
    int i = idx - S6;
    fc1bp[i] = (i < 300) ? fc1b[i] : 0.f;
  } else if (idx < S8) {
    int i = idx - S7, b = i / 320, e = i - b * 320;
    float v = (e < 300) ? embt[(size_t)x[b] * 300 + e] : 0.f;
    ginbf[(size_t)b * 832 + 512 + e] = f2bf(v);
  }
}

// ---------------------------------------------------------------------------
// Generic bf16 GEMM (unchanged from R2): C = A@B^T + bias, tile 128x128.
// ---------------------------------------------------------------------------
template <int EPI>
__global__ __launch_bounds__(256, 3) void gemm_bt(
    const us* __restrict__ A, int lda, const us* __restrict__ Bm, int ldb,
    const float* __restrict__ bias, void* __restrict__ Cp, int ldc, int K) {
  __shared__ us As[128 * 64];
  __shared__ us Bs[128 * 64];
  int tid = threadIdx.x;
  int bm = blockIdx.x * 128, bn = blockIdx.y * 128;
  int lane = tid & 63, wave = tid >> 6;
  int l15 = lane & 15, l4 = lane >> 4;
  int wm = (wave >> 1) * 64, wn = (wave & 1) * 64;

  floatx4 zero = {0.f, 0.f, 0.f, 0.f};
  floatx4 acc[4][4];
#pragma unroll
  for (int i = 0; i < 4; ++i)
#pragma unroll
    for (int j = 0; j < 4; ++j) acc[i][j] = zero;

  int row = tid >> 1;
  int gc0 = (tid & 1) * 4;
  const us* Aptr = A + (size_t)(bm + row) * lda + gc0 * 8;
  const us* Bptr = Bm + (size_t)(bn + row) * ldb + gc0 * 8;
  int rslot7 = row & 7, lslot7 = l15 & 7;

  uint4 pa[4], pb[4];
#pragma unroll
  for (int i = 0; i < 4; ++i) {
    pa[i] = *(const uint4*)(Aptr + i * 8);
    pb[i] = *(const uint4*)(Bptr + i * 8);
  }

  int nk = K >> 6;
  for (int kt = 0; kt < nk; ++kt) {
    if (kt) __syncthreads();
#pragma unroll
    for (int i = 0; i < 4; ++i) {
      int slot = (gc0 + i) ^ rslot7;
      *(uint4*)&As[row * 64 + slot * 8] = pa[i];
      *(uint4*)&Bs[row * 64 + slot * 8] = pb[i];
    }
    __syncthreads();
    if (kt + 1 < nk) {
#pragma unroll
      for (int i = 0; i < 4; ++i) {
        pa[i] = *(const uint4*)(Aptr + (kt + 1) * 64 + i * 8);
        pb[i] = *(const uint4*)(Bptr + (kt + 1) * 64 + i * 8);
      }
    }
#pragma unroll
    for (int ks = 0; ks < 2; ++ks) {
      int slot = (ks * 4 + l4) ^ lslot7;
      short8 av[4], bv[4];
#pragma unroll
      for (int mt = 0; mt < 4; ++mt)
        av[mt] = *(const short8*)&As[(wm + mt * 16 + l15) * 64 + slot * 8];
#pragma unroll
      for (int nt = 0; nt < 4; ++nt)
        bv[nt] = *(const short8*)&Bs[(wn + nt * 16 + l15) * 64 + slot * 8];
#pragma unroll
      for (int mt = 0; mt < 4; ++mt)
#pragma unroll
        for (int nt = 0; nt < 4; ++nt)
          acc[mt][nt] = __builtin_amdgcn_mfma_f32_16x16x32_bf16(
              av[mt], bv[nt], acc[mt][nt], 0, 0, 0);
    }
  }

#pragma unroll
  for (int nt = 0; nt < 4; ++nt) {
    int n = bn + wn + nt * 16 + l15;
    float bvv = bias[n];
#pragma unroll
    for (int mt = 0; mt < 4; ++mt) {
#pragma unroll
      for (int r = 0; r < 4; ++r) {
        int m = bm + wm + mt * 16 + l4 * 4 + r;
        float v = acc[mt][nt][r] + bvv;
        if (EPI == 1) {
          v = v > 0.f ? v : 0.01f * v;
          ((us*)Cp)[(size_t)m * ldc + n] = f2bf(v);
        } else {
          ((float*)Cp)[(size_t)m * ldc + n] = v;
        }
      }
    }
  }
}

// ---------------------------------------------------------------------------
// Fused attention, 1024 threads (16 waves = 4/SIMD). One block per b.
// Wave w owns 32 n-cols. Per kt: pack+write enc tile (disjoint LDS -> one
// barrier), issue W1 bv loads FIRST, then enc prefetch for kt+1 (so vmcnt
// waits on bv leave enc in flight), then MFMA. Epilogue: tanh dot Vw ->
// logits -> softmax -> ctx from LDS-resident enc. enc read from HBM once.
// ---------------------------------------------------------------------------
#define ATTN_LDS_BYTES (131072 + 512 + 512 + 3 * 512 * 4)

__global__ __launch_bounds__(1024, 4) void attn_kernel(
    const float* __restrict__ enc, const us* __restrict__ W1b16,
    const float* __restrict__ keygh, const float* __restrict__ Vw,
    us* __restrict__ gin) {
  extern __shared__ unsigned char smem[];
  us* Albs = (us*)smem;                               // 8 tiles x [128][64]
  float* lds_logits = (float*)(smem + 131072);        // 128 f32
  float* lds_attw = lds_logits + 128;                 // 128 f32
  float* lds_ctx = lds_attw + 128;                    // 3*512 f32

  int b = blockIdx.x, tid = threadIdx.x;
  const float* encb = enc + (size_t)b * 65536;
  if (tid < 128) lds_logits[tid] = 0.f;

  int wave = tid >> 6, lane = tid & 63;
  int l15 = lane & 15, l4 = lane >> 4, lslot7 = l15 & 7;
  int n0 = wave * 32;

  // staging map: thread t -> row t>>3 (0..127), granule t&7 (0..7)
  int srow = tid >> 3, g0 = tid & 7;
  int slotW = g0 ^ (srow & 7);
  const float* sp = encb + srow * 512 + g0 * 8;
  us* wbase = Albs + srow * 64 + slotW * 8;

  floatx4 zero = {0.f, 0.f, 0.f, 0.f};
  floatx4 acc[8][2];
#pragma unroll
  for (int i = 0; i < 8; ++i) {
    acc[i][0] = zero;
    acc[i][1] = zero;
  }

  const us* wptr = W1b16 + (size_t)(n0 + l15) * 512 + l4 * 8;

  float4 p0, p1;                                      // prefetch kt=0
  p0 = *(const float4*)(sp + 0);
  p1 = *(const float4*)(sp + 4);

  for (int kt = 0; kt < 8; ++kt) {
    uint4 q;
    q.x = pack2(p0.x, p0.y);
    q.y = pack2(p0.z, p0.w);
    q.z = pack2(p1.x, p1.y);
    q.w = pack2(p1.z, p1.w);
    *(uint4*)(wbase + kt * 8192) = q;
    __syncthreads();                                  // writes(kt) -> reads(kt)

    // W1 fragments for this kt FIRST (both ks, both nt)
    short8 bv[2][2];
#pragma unroll
    for (int ks = 0; ks < 2; ++ks)
#pragma unroll
      for (int nt = 0; nt < 2; ++nt)
        bv[ks][nt] =
            *(const short8*)(wptr + (size_t)nt * 16 * 512 + kt * 64 + ks * 32);

    // enc prefetch for kt+1 AFTER bv: vmcnt waits on bv won't drain these
    if (kt < 7) {
      const float* np = sp + (kt + 1) * 64;
      p0 = *(const float4*)(np + 0);
      p1 = *(const float4*)(np + 4);
    }

    const us* rb = Albs + kt * 8192;
#pragma unroll
    for (int ks = 0; ks < 2; ++ks) {
      int slot = (ks * 4 + l4) ^ lslot7;
#pragma unroll
      for (int mt = 0; mt < 8; ++mt) {
        short8 av = *(const short8*)(rb + (mt * 16 + l15) * 64 + slot * 8);
        acc[mt][0] = __builtin_amdgcn_mfma_f32_16x16x32_bf16(
            av, bv[ks][0], acc[mt][0], 0, 0, 0);
        acc[mt][1] = __builtin_amdgcn_mfma_f32_16x16x32_bf16(
            av, bv[ks][1], acc[mt][1], 0, 0, 0);
      }
    }
  }

  // ---- epilogue: logits[s] += sum_j tanh(score+key[j]) * Vw[j] ----
  float kb[2], vwl[2];
#pragma unroll
  for (int nt = 0; nt < 2; ++nt) {
    int col = n0 + nt * 16 + l15;
    kb[nt] = keygh[(size_t)b * 2048 + col];
    vwl[nt] = Vw[col];
  }
#pragma unroll
  for (int mt = 0; mt < 8; ++mt) {
#pragma unroll
    for (int r = 0; r < 4; ++r) {
      float c = tanh_fast(acc[mt][0][r] + kb[0]) * vwl[0] +
                tanh_fast(acc[mt][1][r] + kb[1]) * vwl[1];
      c += __shfl_xor(c, 1, 64);
      c += __shfl_xor(c, 2, 64);
      c += __shfl_xor(c, 4, 64);
      c += __shfl_xor(c, 8, 64);
      if (l15 == 0) atomicAdd(&lds_logits[mt * 16 + l4 * 4 + r], c);
    }
  }
  __syncthreads();

  // ---- softmax over S=128 (wave 0; V_b dropped: shift-invariant) ----
  if (wave == 0) {
    float v0 = lds_logits[lane], v1 = lds_logits[lane + 64];
    float mx = fmaxf(v0, v1);
#pragma unroll
    for (int o = 32; o >= 1; o >>= 1) mx = fmaxf(mx, __shfl_xor(mx, o, 64));
    float e0 = __expf(v0 - mx), e1 = __expf(v1 - mx);
    float s = e0 + e1;
#pragma unroll
    for (int o = 32; o >= 1; o >>= 1) s += __shfl_xor(s, o, 64);
    float inv = 1.f / s;
    lds_attw[lane] = e0 * inv;
    lds_attw[lane + 64] = e1 * inv;
  }
  __syncthreads();

  // ---- ctx: 4 s-quarters x 256 threads; thread handles h-pair (dword) ----
  int pr = tid & 255, sh = tid >> 8;                  // sh in 0..3
  int h0 = pr * 2;
  int ktc = h0 >> 6, gclc = (h0 & 63) >> 3, dofs = h0 & 7;  // shorts
  const us* cb = Albs + ktc * 8192;
  float c0 = 0.f, c1 = 0.f;
  int sbeg = sh * 32;
  for (int s = sbeg; s < sbeg + 32; ++s) {
    int slot = gclc ^ (s & 7);
    unsigned d = *(const unsigned*)(cb + s * 64 + slot * 8 + dofs);
    float aw = lds_attw[s];
    c0 += aw * bf2f((us)(d & 0xffffu));
    c1 += aw * bf2f((us)(d >> 16));
  }
  if (sh != 0) {
    lds_ctx[(sh - 1) * 512 + h0] = c0;
    lds_ctx[(sh - 1) * 512 + h0 + 1] = c1;
  }
  __syncthreads();
  if (sh == 0) {
    c0 += lds_ctx[h0] + lds_ctx[512 + h0] + lds_ctx[1024 + h0];
    c1 += lds_ctx[h0 + 1] + lds_ctx[512 + h0 + 1] + lds_ctx[1024 + h0 + 1];
    *(unsigned*)(gin + (size_t)b * 832 + h0) = pack2(c0, c1);
  }
}

// ---------------------------------------------------------------------------
// GRU elementwise (unchanged): gh lives in keygh cols [512,2048).
// ---------------------------------------------------------------------------
__global__ void gru_kernel(const float* __restrict__ gi,
                           const float* __restrict__ keygh,
                           const float* __restrict__ hidden,
                           float* __restrict__ outh,
                           us* __restrict__ hnewbf) {
  int idx = blockIdx.x * 256 + threadIdx.x;   // 2048*512
  int b = idx >> 9, h = idx & 511;
  const float* gib = gi + (size_t)b * 1536;
  const float* ghb = keygh + (size_t)b * 2048 + 512;
  float r = sigmoid_fast(gib[h] + ghb[h]);
  float z = sigmoid_fast(gib[512 + h] + ghb[512 + h]);
  float n = tanh_fast(gib[1024 + h] + r * ghb[1024 + h]);
  float h0 = hidden[idx];
  float hn = (1.f - z) * n + z * h0;
  outh[idx] = hn;
  hnewbf[idx] = f2bf(hn);
}

// ---------------------------------------------------------------------------
extern "C" void kernel_launch(void* const* d_in, const int* in_sizes, int n_in,
                              void* d_out, int out_size, void* d_ws,
                              size_t ws_size, hipStream_t stream) {
  const int* x = (const int*)d_in[0];
  const float* hidden = (const float*)d_in[1];
  const float* enc = (const float*)d_in[2];
  const float* embt = (const float*)d_in[3];
  const float* W1w = (const float*)d_in[4];
  const float* W1b = (const float*)d_in[5];
  const float* W2w = (const float*)d_in[6];
  const float* W2b = (const float*)d_in[7];
  const float* Vw = (const float*)d_in[8];
  const float* wih = (const float*)d_in[10];
  const float* whh = (const float*)d_in[11];
  const float* bih = (const float*)d_in[12];
  const float* bhh = (const float*)d_in[13];
  const float* fc1w = (const float*)d_in[14];
  const float* fc1b = (const float*)d_in[15];
  const float* fc2w = (const float*)d_in[16];
  const float* fc2b = (const float*)d_in[17];

  float* out_y = (float*)d_out;                  // (2048,128)
  float* out_h = out_y + 2048 * 128;             // (2048,512)

  char* ws = (char*)d_ws;
  size_t o = 0;
  auto alloc = [&](size_t bytes) {
    size_t r = o;
    o += (bytes + 255) & ~(size_t)255;
    return r;
  };
  us* W1bf   = (us*)(ws + alloc(512 * 512 * 2));
  us* wcomb  = (us*)(ws + alloc(2048 * 512 * 2));
  us* wihbf  = (us*)(ws + alloc(1536 * 832 * 2));
  us* fc1wbf = (us*)(ws + alloc(384 * 512 * 2));
  us* fc2wbf = (us*)(ws + alloc(128 * 384 * 2));
  us* hidbf  = (us*)(ws + alloc(2048 * 512 * 2));
  float* bcomb = (float*)(ws + alloc(2048 * 4));
  float* fc1bp = (float*)(ws + alloc(384 * 4));
  us* ginbf  = (us*)(ws + alloc((size_t)2048 * 832 * 2));
  float* keygh = (float*)(ws + alloc((size_t)2048 * 2048 * 4));
  float* gi    = (float*)(ws + alloc((size_t)2048 * 1536 * 4));
  us* hnewbf = (us*)(ws + alloc(2048 * 512 * 2));
  us* a1bf   = (us*)(ws + alloc((size_t)2048 * 384 * 2));

  // 1) fused prep
  prep_kernel<<<(S8 + 255) / 256, 256, 0, stream>>>(
      W1w, W2w, whh, wih, fc1w, fc2w, hidden, W1b, W2b, bhh, fc1b, x, embt,
      W1bf, wcomb, wihbf, fc1wbf, fc2wbf, hidbf, bcomb, fc1bp, ginbf);

  // 2) keygh = h0 @ [W2;whh]^T + [W1b+W2b; bhh]   (2048x2048)
  gemm_bt<0><<<dim3(16, 16), 256, 0, stream>>>(hidbf, 512, wcomb, 512, bcomb,
                                               (void*)keygh, 2048, 512);

  // 3) fused attention -> ctx into gin[:, 0:512]
  (void)hipFuncSetAttribute((const void*)attn_kernel,
                            hipFuncAttributeMaxDynamicSharedMemorySize,
                            ATTN_LDS_BYTES);
  attn_kernel<<<2048, 1024, ATTN_LDS_BYTES, stream>>>(enc, W1bf, keygh, Vw,
                                                      ginbf);

  // 4) gi = gin @ w_ih^T + b_ih   (2048x1536, K=832)
  gemm_bt<0><<<dim3(16, 12), 256, 0, stream>>>(ginbf, 832, wihbf, 832, bih,
                                               (void*)gi, 1536, 832);

  // 5) GRU gates -> h_new (f32 out + bf16 copy)
  gru_kernel<<<2048 * 512 / 256, 256, 0, stream>>>(gi, keygh, hidden, out_h,
                                                   hnewbf);

  // 6) head
  gemm_bt<1><<<dim3(16, 3), 256, 0, stream>>>(hnewbf, 512, fc1wbf, 512, fc1bp,
                                              (void*)a1bf, 384, 512);
  gemm_bt<0><<<dim3(16, 1), 256, 0, stream>>>(a1bf, 384, fc2wbf, 384, fc2b,
                                              (void*)out_y, 128, 384);
}